// Round 4
// baseline (1635.998 us; speedup 1.0000x reference)
//
#include <hip/hip_runtime.h>
#include <hip/hip_bf16.h>
#include <hip/hip_cooperative_groups.h>

namespace cg = cooperative_groups;

// GCN via CSR counting-sort, CSR built in ONE cooperative kernel with all
// atomics XCD-local (L2-side). Round-3 profile: scatter = 262us, 198MB
// writes = 3.2M memory-side cursor atomics + random 8B stores evicting
// dirty lines early. Same-workgroup = same-XCD across phases makes per-XCD
// sub-buckets exact; fences + grid.sync give cross-XCD visibility.
//   phase1: cnt8[x][d]++, deg8[x][d]+=w   (XCD-local atomics)
//   phase2: dinv = rsqrt(1+deg), row_start scan, per-XCD cursors
//   phase3: sorted[pos] = (src, dinv[s]*w*dinv[d])  (XCD-local cursor atomics)
// Then: t = x@W1 -> agg1 (fused self-term+bias+relu) = h1
//       -> agg2 fused with @W2+b2+log_softmax -> out.

#define D_IN 512
#define D_HID 16
#define D_OUT 64
#define GBLK 1024
#define BT 256

__device__ __forceinline__ int xcc_id() {
    int id;
    asm volatile("s_getreg_b32 %0, hwreg(HW_REG_XCC_ID)" : "=s"(id));
    return id & 7;
}

__global__ __launch_bounds__(BT) void csr_build_kernel(
        const int* __restrict__ src, const int* __restrict__ dst,
        const float* __restrict__ w,
        int* __restrict__ cnt8, float* __restrict__ deg8,  // deg8 re-used as cursor8
        int* __restrict__ row_start, float* __restrict__ dinv,
        int* __restrict__ bsum, float2* __restrict__ sorted,
        int N, int E) {
    cg::grid_group grid = cg::this_grid();
    const int x = xcc_id();
    const int tid = threadIdx.x;
    const int gtid = blockIdx.x * BT + tid;
    const int gsz = GBLK * BT;
    int* cursor8 = (int*)deg8;

    // ---- phase 1: per-XCD histogram + weighted degree ----
    for (int e = gtid; e < E; e += gsz) {
        int d = dst[e];
        __hip_atomic_fetch_add(&cnt8[(size_t)x * N + d], 1,
                               __ATOMIC_RELAXED, __HIP_MEMORY_SCOPE_WORKGROUP);
        __hip_atomic_fetch_add(&deg8[(size_t)x * N + d], w[e],
                               __ATOMIC_RELAXED, __HIP_MEMORY_SCOPE_WORKGROUP);
    }
    __threadfence();  // agent-scope release: write back XCD L2
    grid.sync();
    __threadfence();  // agent-scope acquire: invalidate stale lines

    // ---- phase 2a: per-node totals, dinv, block-local scan ----
    __shared__ int ex[BT];
    __shared__ int tot_s[BT];
    const int chunk = (N + GBLK - 1) / GBLK;   // 98 for N=100000
    const int n = blockIdx.x * chunk + tid;
    int tot = 0;
    if (tid < chunk && n < N) {
        float dg = 0.0f;
#pragma unroll
        for (int xx = 0; xx < 8; ++xx) {
            tot += cnt8[(size_t)xx * N + n];
            dg  += deg8[(size_t)xx * N + n];
        }
        dinv[n] = __frsqrt_rn(1.0f + dg);
    }
    tot_s[tid] = tot;
    ex[tid] = tot;
    __syncthreads();
    for (int off = 1; off < BT; off <<= 1) {
        int v = (tid >= off) ? ex[tid - off] : 0;
        __syncthreads();
        ex[tid] += v;
        __syncthreads();
    }
    if (tid == BT - 1) bsum[blockIdx.x] = ex[BT - 1];
    __threadfence();
    grid.sync();
    __threadfence();

    // ---- phase 2b: global base, row_start, per-XCD cursors ----
    int part = 0;
    for (int i = tid; i < blockIdx.x; i += BT) part += bsum[i];
#pragma unroll
    for (int off = 32; off; off >>= 1) part += __shfl_down(part, off, 64);
    __shared__ int wred[BT / 64];
    if ((tid & 63) == 0) wred[tid >> 6] = part;
    __syncthreads();
    int bbase = 0;
#pragma unroll
    for (int i = 0; i < BT / 64; ++i) bbase += wred[i];

    if (tid < chunk && n < N) {
        int rs = bbase + ex[tid] - tot_s[tid];  // exclusive scan value
        row_start[n] = rs;
        int c = rs;
#pragma unroll
        for (int xx = 0; xx < 8; ++xx) {
            cursor8[(size_t)xx * N + n] = c;
            c += cnt8[(size_t)xx * N + n];
        }
    }
    if (gtid == 0) row_start[N] = E;
    __threadfence();
    grid.sync();
    __threadfence();

    // ---- phase 3: scatter (same workgroup => same XCD as phase 1) ----
    for (int e = gtid; e < E; e += gsz) {
        int s = src[e], d = dst[e];
        float nm = dinv[s] * w[e] * dinv[d];
        int pos = __hip_atomic_fetch_add(&cursor8[(size_t)x * N + d], 1,
                                         __ATOMIC_RELAXED, __HIP_MEMORY_SCOPE_WORKGROUP);
        sorted[pos] = make_float2(__int_as_float(s), nm);
    }
}

// t[N][16] = x[N][512] @ W1[512][16]; 16 lanes/row, each owns 8 float4 k-slices.
__global__ __launch_bounds__(256) void gemm1_kernel(const float* __restrict__ x,
                                                    const float* __restrict__ W1,
                                                    float* __restrict__ t, int N) {
    __shared__ float w1t[16 * 520];
    for (int idx = threadIdx.x; idx < D_IN * D_HID; idx += 256) {
        int k = idx >> 4, j = idx & 15;
        w1t[j * 520 + k] = W1[idx];
    }
    __syncthreads();

    const int wave = threadIdx.x >> 6;
    const int lane = threadIdx.x & 63;
    const int g = lane >> 4;
    const int s = lane & 15;

    for (int base = blockIdx.x * 16; base < N; base += gridDim.x * 16) {
        int row = base + wave * 4 + g;
        if (row < N) {
            const float4* xr = (const float4*)(x + (size_t)row * D_IN);
            float4 xv[8];
#pragma unroll
            for (int i = 0; i < 8; ++i) xv[i] = xr[s + 16 * i];
            float acc[16];
#pragma unroll
            for (int j = 0; j < 16; ++j) acc[j] = 0.0f;
#pragma unroll
            for (int i = 0; i < 8; ++i) {
                int kb = 4 * s + 64 * i;
#pragma unroll
                for (int j = 0; j < 16; ++j) {
                    const float4 wv = *(const float4*)&w1t[j * 520 + kb];
                    acc[j] += xv[i].x * wv.x + xv[i].y * wv.y + xv[i].z * wv.z + xv[i].w * wv.w;
                }
            }
#pragma unroll
            for (int j = 0; j < 16; ++j) {
#pragma unroll
                for (int m = 1; m < 16; m <<= 1) acc[j] += __shfl_xor(acc[j], m, 64);
            }
            float v = acc[0];
#pragma unroll
            for (int j = 1; j < 16; ++j) v = (s == j) ? acc[j] : v;
            t[(size_t)row * 16 + s] = v;
        }
    }
}

// Layer-1 aggregation. One wave per node; lane = k*4+q: 16 edges in flight,
// each edge's 16-dim feature row read as 4 lanes x float4 (one 64B line).
// h1 = relu(edge_sum + dinv^2 * t + b1).  norm already baked into sorted.
__global__ __launch_bounds__(256) void agg1_kernel(const float2* __restrict__ sorted,
                                                   const int* __restrict__ row_start,
                                                   const float* __restrict__ feat,
                                                   const float* __restrict__ dinv,
                                                   const float* __restrict__ b1,
                                                   float* __restrict__ outp, int N) {
    int node = blockIdx.x * 4 + (threadIdx.x >> 6);
    if (node >= N) return;
    const int lane = threadIdx.x & 63;
    const int q = lane & 3, k = lane >> 2;
    const int beg = row_start[node], end = row_start[node + 1];
    float4 acc = make_float4(0.f, 0.f, 0.f, 0.f);
    for (int e = beg + k; e < end; e += 16) {
        float2 p = sorted[e];
        int s = __float_as_int(p.x);
        const float4 f = *(const float4*)(feat + (size_t)s * 16 + q * 4);
        acc.x += p.y * f.x; acc.y += p.y * f.y; acc.z += p.y * f.z; acc.w += p.y * f.w;
    }
#pragma unroll
    for (int m = 4; m < 64; m <<= 1) {
        acc.x += __shfl_xor(acc.x, m, 64);
        acc.y += __shfl_xor(acc.y, m, 64);
        acc.z += __shfl_xor(acc.z, m, 64);
        acc.w += __shfl_xor(acc.w, m, 64);
    }
    float dn = dinv[node];
    float dn2 = dn * dn;
    if (k == 0) {
        const float4 sv = *(const float4*)(feat + (size_t)node * 16 + q * 4);
        const float4 bb = *(const float4*)(b1 + q * 4);
        float4 r;
        r.x = fmaxf(acc.x + dn2 * sv.x + bb.x, 0.0f);
        r.y = fmaxf(acc.y + dn2 * sv.y + bb.y, 0.0f);
        r.z = fmaxf(acc.z + dn2 * sv.z + bb.z, 0.0f);
        r.w = fmaxf(acc.w + dn2 * sv.w + bb.w, 0.0f);
        *(float4*)(outp + (size_t)node * 16 + q * 4) = r;
    }
}

// Layer-2 aggregation fused with @W2 + b2 + log_softmax. Same gather layout;
// after the xor-reduce every lane holds the full 4-dim slice for its q, so
// the 16-dim v is broadcast via 16 shuffles into the 64-wide GEMM.
__global__ __launch_bounds__(256) void agg2out_kernel(const float2* __restrict__ sorted,
                                                      const int* __restrict__ row_start,
                                                      const float* __restrict__ h1,
                                                      const float* __restrict__ dinv,
                                                      const float* __restrict__ W2,
                                                      const float* __restrict__ b2,
                                                      float* __restrict__ out, int N) {
    __shared__ float w2s[16 * 64];
    __shared__ float b2s[64];
    for (int idx = threadIdx.x; idx < 16 * 64; idx += 256) w2s[idx] = W2[idx];
    if (threadIdx.x < 64) b2s[threadIdx.x] = b2[threadIdx.x];
    __syncthreads();

    int node = blockIdx.x * 4 + (threadIdx.x >> 6);
    if (node >= N) return;
    const int lane = threadIdx.x & 63;
    const int q = lane & 3, k = lane >> 2;
    const int beg = row_start[node], end = row_start[node + 1];
    float4 acc = make_float4(0.f, 0.f, 0.f, 0.f);
    for (int e = beg + k; e < end; e += 16) {
        float2 p = sorted[e];
        int s = __float_as_int(p.x);
        const float4 f = *(const float4*)(h1 + (size_t)s * 16 + q * 4);
        acc.x += p.y * f.x; acc.y += p.y * f.y; acc.z += p.y * f.z; acc.w += p.y * f.w;
    }
#pragma unroll
    for (int m = 4; m < 64; m <<= 1) {
        acc.x += __shfl_xor(acc.x, m, 64);
        acc.y += __shfl_xor(acc.y, m, 64);
        acc.z += __shfl_xor(acc.z, m, 64);
        acc.w += __shfl_xor(acc.w, m, 64);
    }
    float dn = dinv[node];
    float dn2 = dn * dn;
    const float4 hv = *(const float4*)(h1 + (size_t)node * 16 + q * 4);
    float vc[4];
    vc[0] = acc.x + dn2 * hv.x;
    vc[1] = acc.y + dn2 * hv.y;
    vc[2] = acc.z + dn2 * hv.z;
    vc[3] = acc.w + dn2 * hv.w;

    float z = b2s[lane];
#pragma unroll
    for (int j = 0; j < 16; ++j) {
        float vj = __shfl(vc[j & 3], j >> 2, 64);  // source lane k=0, q=j>>2
        z += vj * w2s[j * 64 + lane];
    }
    float m = z;
#pragma unroll
    for (int off = 32; off; off >>= 1) m = fmaxf(m, __shfl_xor(m, off, 64));
    float ez = __expf(z - m);
    float ssum = ez;
#pragma unroll
    for (int off = 32; off; off >>= 1) ssum += __shfl_xor(ssum, off, 64);
    out[(size_t)node * 64 + lane] = z - m - __logf(ssum);
}

extern "C" void kernel_launch(void* const* d_in, const int* in_sizes, int n_in,
                              void* d_out, int out_size, void* d_ws, size_t ws_size,
                              hipStream_t stream) {
    const float* x  = (const float*)d_in[0];
    const int*   ei = (const int*)d_in[1];
    const float* ew = (const float*)d_in[2];
    const float* W1 = (const float*)d_in[3];
    const float* b1 = (const float*)d_in[4];
    const float* W2 = (const float*)d_in[5];
    const float* b2 = (const float*)d_in[6];
    float* out = (float*)d_out;

    int N = in_sizes[0] / D_IN;
    int E = in_sizes[2];
    const int* srcI = ei;
    const int* dstI = ei + E;

    // ws layout (float units):
    //   [0, 16N)        : cnt8[8N] + deg8/cursor8[8N]  -- later reused as t[16N]
    //   [16N, 17N+2)    : row_start
    //   [17N+2, 18N+2)  : dinv
    //   [18N+2, +1024)  : bsum
    //   [18N+1026, +16N): h1
    //   [34N+1026, +2E) : sorted (float2 per edge)
    float* ws = (float*)d_ws;
    float*  t         = ws;
    int*    cnt8      = (int*)ws;
    float*  deg8      = ws + 8 * (size_t)N;
    int*    row_start = (int*)(ws + 16 * (size_t)N);
    float*  dinv      = ws + 17 * (size_t)N + 2;
    int*    bsum      = (int*)(ws + 18 * (size_t)N + 2);
    float*  h1        = ws + 18 * (size_t)N + 1026;
    float2* sorted    = (float2*)(ws + 34 * (size_t)N + 1026);

    hipMemsetAsync(cnt8, 0, (size_t)16 * N * sizeof(float), stream);  // cnt8 + deg8

    void* args[] = {(void*)&srcI, (void*)&dstI, (void*)&ew, (void*)&cnt8, (void*)&deg8,
                    (void*)&row_start, (void*)&dinv, (void*)&bsum, (void*)&sorted,
                    (void*)&N, (void*)&E};
    hipLaunchCooperativeKernel((const void*)csr_build_kernel, dim3(GBLK), dim3(BT),
                               args, 0, stream);

    gemm1_kernel<<<1024, 256, 0, stream>>>(x, W1, t, N);

    agg1_kernel<<<(N + 3) / 4, 256, 0, stream>>>(sorted, row_start, t, dinv, b1, h1, N);
    agg2out_kernel<<<(N + 3) / 4, 256, 0, stream>>>(sorted, row_start, h1, dinv, W2, b2, out, N);
}